// Round 7
// baseline (731.964 us; speedup 1.0000x reference)
//
#include <hip/hip_runtime.h>
#include <cstdint>
#include <cstddef>

#define CH 256      // all layers are 256-channel

typedef _Float16 f16x8 __attribute__((ext_vector_type(8)));
typedef float f32x4 __attribute__((ext_vector_type(4)));
typedef float f32x2 __attribute__((ext_vector_type(2)));

#define GLOB(x) ((const __attribute__((address_space(1))) void*)(x))
#define LDSP(x) ((__attribute__((address_space(3))) void*)(x))

// ---------------- helpers ----------------

__device__ __forceinline__ int ld_idx(const void* p, long long i, int w64) {
    if (w64) return (int)((const long long*)p)[i];
    return ((const int*)p)[i];
}

__device__ __forceinline__ float gelu_f(float x) {
    float x3 = x * x * x;
    float t = tanhf(0.7978845608028654f * (x + 0.044715f * x3));
    return 0.5f * x * (1.0f + t);
}

// ---------------- preprocessing ----------------

__global__ void k_detect(const void* __restrict__ ei, int* __restrict__ flag, int E) {
    int l = threadIdx.x;  // 0..63
    long long k = ((long long)l * (long long)(E - 1)) / 63;
    int w = ((const int*)ei)[2 * k + 1];
    unsigned long long vote = __ballot(w == 0);
    if (l == 0) *flag = (vote == ~0ULL) ? 1 : 0;
}

__global__ void k_deg(const void* __restrict__ ei, const int* __restrict__ flag,
                      int* __restrict__ deg, int E) {
    int e = blockIdx.x * blockDim.x + threadIdx.x;
    if (e >= E) return;
    int w64 = *flag;
    int d = ld_idx(ei, (long long)E + e, w64);
    atomicAdd(&deg[d], 1);
}

__global__ void k_dis(const int* __restrict__ deg, float* __restrict__ dis, int N) {
    int n = blockIdx.x * blockDim.x + threadIdx.x;
    if (n >= N) return;
    dis[n] = 1.0f / sqrtf((float)(deg[n] + 1));
}

__global__ void k_scan_block(const int* __restrict__ deg, int* __restrict__ rowptr,
                             int* __restrict__ partial, int N) {
    __shared__ int s[256];
    int gid = blockIdx.x * 256 + threadIdx.x;
    int v = (gid < N) ? deg[gid] : 0;
    s[threadIdx.x] = v;
    __syncthreads();
    for (int off = 1; off < 256; off <<= 1) {
        int t = (threadIdx.x >= off) ? s[threadIdx.x - off] : 0;
        __syncthreads();
        s[threadIdx.x] += t;
        __syncthreads();
    }
    if (gid < N) rowptr[gid] = s[threadIdx.x] - v;
    if (threadIdx.x == 255) partial[blockIdx.x] = s[255];
}

__global__ void k_scan_partial(int* __restrict__ partial, int nb) {
    __shared__ int s[256];
    int i = threadIdx.x;
    int v = (i < nb) ? partial[i] : 0;
    s[i] = v;
    __syncthreads();
    for (int off = 1; off < 256; off <<= 1) {
        int t = (i >= off) ? s[i - off] : 0;
        __syncthreads();
        s[i] += t;
        __syncthreads();
    }
    if (i < nb) partial[i] = s[i] - v;
}

__global__ void k_add_off(int* __restrict__ rowptr, const int* __restrict__ partial,
                          int N, int E) {
    int gid = blockIdx.x * 256 + threadIdx.x;
    if (gid < N) rowptr[gid] += partial[blockIdx.x];
    if (gid == 0) rowptr[N] = E;
}

__global__ void k_scatter(const void* __restrict__ ei, const int* __restrict__ flag,
                          const float* __restrict__ dis, const int* __restrict__ rowptr,
                          int* __restrict__ cnt, int2* __restrict__ epack, int E) {
    int e = blockIdx.x * blockDim.x + threadIdx.x;
    if (e >= E) return;
    int w64 = *flag;
    int s = ld_idx(ei, e, w64);
    int d = ld_idx(ei, (long long)E + e, w64);
    int pos = rowptr[d] + atomicAdd(&cnt[d], 1);
    epack[pos] = make_int2(s, __float_as_int(dis[s] * dis[d]));
}

// ---------------- weight split: W[k][c] fp32 -> Wt hi/lo fp16 [c][k] ----------------

__global__ void k_split_w(const float* __restrict__ W, _Float16* __restrict__ Wh,
                          _Float16* __restrict__ Wl) {
    int k = threadIdx.x;   // 0..255
    int c = blockIdx.x;    // 0..255
    float v = W[k * CH + c];
    _Float16 h = (_Float16)v;
    Wh[c * CH + k] = h;
    Wl[c * CH + k] = (_Float16)(v - (float)h);
}

// ---------------- fp16x2 split GEMM via MFMA, int16-quantized channel-major output ----
// H16g layout: [8 groups][M nodes][32 ch int16] (group = 3.2 MB, L2-resident per XCD).
// Per-(node,half) scale in scales[node*2+half].
// Block: 128x128 output, 4 waves of 64x64, MFMA 16x16x32_f16, K-step 32.

#define GM 128
#define GN 128
#define GK 32

__global__ __launch_bounds__(256, 2)
void k_gemm16(const float* __restrict__ A, const _Float16* __restrict__ Bh,
              const _Float16* __restrict__ Bl, uint8_t* __restrict__ H16,
              float* __restrict__ scales, int M) {
    __shared__ __align__(16) char smem[65536];
    float*    lA = (float*)smem;              // [2][128*32] fp32  = 32 KB
    _Float16* lB = (_Float16*)(smem + 32768); // [2][2][128*32] f16 = 32 KB

    const int tid  = threadIdx.x;
    const int lane = tid & 63;
    const int wid  = tid >> 6;
    const int m0   = blockIdx.x * GM;
    const int n0   = blockIdx.y * GN;
    const int wm   = wid >> 1, wn = wid & 1;
    const int r15  = lane & 15, kg = lane >> 4;

    // stage one K-step tile: A = 1024 chunks(16B), Bh = 512, Bl = 512 -> 32 calls, 8/wave
    auto stage = [&](int buf, int k0) {
        #pragma unroll
        for (int c = 0; c < 8; c++) {
            int call = wid * 8 + c;
            if (call < 16) {                        // A fp32: 128 rows x 8 chunks
                int L = call * 64 + lane;
                int row = L >> 3, ch = L & 7;
                int gr = m0 + row; gr = (gr < M) ? gr : (M - 1);
                const float* g = A + (size_t)gr * CH + k0 + ((ch ^ (row & 7)) << 2);
                __builtin_amdgcn_global_load_lds(GLOB(g), LDSP(&lA[buf * 4096 + call * 256]), 16, 0, 0);
            } else if (call < 24) {                 // B hi: 128 rows x 4 chunks
                int cc = call - 16;
                int L = cc * 64 + lane;
                int row = L >> 2, ch = L & 3;
                const _Float16* g = Bh + (size_t)(n0 + row) * CH + k0 + ((ch ^ ((row >> 1) & 3)) << 3);
                __builtin_amdgcn_global_load_lds(GLOB(g), LDSP(&lB[buf * 8192 + cc * 512]), 16, 0, 0);
            } else {                                // B lo
                int cc = call - 24;
                int L = cc * 64 + lane;
                int row = L >> 2, ch = L & 3;
                const _Float16* g = Bl + (size_t)(n0 + row) * CH + k0 + ((ch ^ ((row >> 1) & 3)) << 3);
                __builtin_amdgcn_global_load_lds(GLOB(g), LDSP(&lB[buf * 8192 + 4096 + cc * 512]), 16, 0, 0);
            }
        }
    };

    f32x4 acc[4][4];
    #pragma unroll
    for (int i = 0; i < 4; i++)
        #pragma unroll
        for (int n = 0; n < 4; n++)
            acc[i][n] = (f32x4){0.f, 0.f, 0.f, 0.f};

    stage(0, 0);
    __syncthreads();

    for (int ks = 0; ks < 8; ks++) {
        int cur = ks & 1;
        if (ks < 7) stage(cur ^ 1, (ks + 1) * GK);

        f16x8 ah[4], al[4], bh[4], bl[4];
        #pragma unroll
        for (int i = 0; i < 4; i++) {
            int R  = wm * 64 + i * 16 + r15;
            int p0 = (2 * kg) ^ (R & 7);
            const f32x4* base = (const f32x4*)&lA[cur * 4096 + R * GK];
            f32x4 va = base[p0];
            f32x4 vb = base[p0 ^ 1];
            #pragma unroll
            for (int j = 0; j < 4; j++) {
                float v = va[j];
                _Float16 h = (_Float16)v;
                ah[i][j] = h;
                al[i][j] = (_Float16)(v - (float)h);
            }
            #pragma unroll
            for (int j = 0; j < 4; j++) {
                float v = vb[j];
                _Float16 h = (_Float16)v;
                ah[i][4 + j] = h;
                al[i][4 + j] = (_Float16)(v - (float)h);
            }
        }
        #pragma unroll
        for (int n = 0; n < 4; n++) {
            int C = wn * 64 + n * 16 + r15;
            int p = kg ^ ((C >> 1) & 3);
            bh[n] = *(const f16x8*)&lB[cur * 8192 + C * GK + p * 8];
            bl[n] = *(const f16x8*)&lB[cur * 8192 + 4096 + C * GK + p * 8];
        }
        #pragma unroll
        for (int i = 0; i < 4; i++)
            #pragma unroll
            for (int n = 0; n < 4; n++) {
                acc[i][n] = __builtin_amdgcn_mfma_f32_16x16x32_f16(ah[i], bh[n], acc[i][n], 0, 0, 0);
                acc[i][n] = __builtin_amdgcn_mfma_f32_16x16x32_f16(ah[i], bl[n], acc[i][n], 0, 0, 0);
                acc[i][n] = __builtin_amdgcn_mfma_f32_16x16x32_f16(al[i], bh[n], acc[i][n], 0, 0, 0);
            }
        __syncthreads();
    }

    // ---- epilogue: tile absmax -> scale, transpose via LDS, int16 store (channel-major) ----
    float mx = 0.f;
    #pragma unroll
    for (int i = 0; i < 4; i++)
        #pragma unroll
        for (int n = 0; n < 4; n++)
            #pragma unroll
            for (int r = 0; r < 4; r++)
                mx = fmaxf(mx, fabsf(acc[i][n][r]));
    #pragma unroll
    for (int off = 32; off > 0; off >>= 1)
        mx = fmaxf(mx, __shfl_xor(mx, off));
    if (lane == 0) ((float*)smem)[wid] = mx;
    __syncthreads();
    float tmax = fmaxf(fmaxf(((float*)smem)[0], ((float*)smem)[1]),
                       fmaxf(((float*)smem)[2], ((float*)smem)[3]));
    float scl = tmax * (1.0f / 32767.0f);
    float inv = (tmax > 0.f) ? (32767.0f / tmax) : 0.f;
    __syncthreads();

    float* ep = (float*)smem + wid * 4096;   // 64x64 fp32 tile per wave
    #pragma unroll
    for (int i = 0; i < 4; i++)
        #pragma unroll
        for (int n = 0; n < 4; n++)
            #pragma unroll
            for (int r = 0; r < 4; r++)
                ep[(i * 16 + kg * 4 + r) * 64 + n * 16 + r15] = acc[i][n][r];
    __syncthreads();

    int q = lane & 15;            // channel quad within tile
    int rsub = lane >> 4;         // row sub-index
    #pragma unroll
    for (int p = 0; p < 16; p++) {
        int lrow = p * 4 + rsub;                    // 0..63
        int grow = m0 + wm * 64 + lrow;
        if (grow < M) {
            int q0 = __float2int_rn(ep[lrow * 64 + q * 4 + 0] * inv);
            int q1 = __float2int_rn(ep[lrow * 64 + q * 4 + 1] * inv);
            int q2 = __float2int_rn(ep[lrow * 64 + q * 4 + 2] * inv);
            int q3 = __float2int_rn(ep[lrow * 64 + q * 4 + 3] * inv);
            uint2 d;
            d.x = (q0 & 0xFFFF) | (q1 << 16);
            d.y = (q2 & 0xFFFF) | (q3 << 16);
            int col = n0 + wn * 64 + q * 4;       // global channel 0..255
            uint8_t* dst = H16 + ((size_t)(col >> 5) * (size_t)M + grow) * 64
                               + (size_t)(col & 31) * 2;
            *(uint2*)dst = d;
        }
    }

    if (tid < GM && m0 + tid < M) scales[(size_t)(m0 + tid) * 2 + (n0 >> 7)] = scl;
}

// ---------------- sparse aggregation (channel-partitioned gather) ----------------
// Block handles channel-group g = blockIdx.x & 7 (-> pinned to XCD g by round-robin
// dispatch) and 4 nodes (one per wave). Per edge: 16 lanes read one 64 B row slice
// (L2-resident 3.2 MB group). 4 edge slots per wave, shfl reduce at the end.

__global__ __launch_bounds__(256) void k_agg(const uint8_t* __restrict__ H16g,
                                             const float* __restrict__ scales,
                                             const float* __restrict__ dis,
                                             const int* __restrict__ rowptr,
                                             const int2* __restrict__ epack,
                                             const float* __restrict__ bias,
                                             float* __restrict__ out, int N, int do_gelu) {
    int g = blockIdx.x & 7;
    int node = (blockIdx.x >> 3) * 4 + threadIdx.y;
    if (node >= N) return;
    int lane = threadIdx.x;          // 0..63
    int sub = lane >> 4;             // edge slot 0..3
    int cp  = lane & 15;             // channel pair 0..15 (2 ch each)
    int half = g >> 2;
    const uint8_t* __restrict__ Hg = H16g + (size_t)g * (size_t)N * 64;

    // self term (slot 0 only)
    float ax, ay;
    {
        unsigned u = *(const unsigned*)(Hg + (size_t)node * 64 + cp * 4);
        float d = dis[node];
        float ws = (sub == 0) ? d * d * scales[(size_t)node * 2 + half] : 0.f;
        ax = ws * (float)(short)(u & 0xFFFFu);
        ay = ws * (float)(short)(u >> 16);
    }

    int s = rowptr[node], e = rowptr[node + 1];
    float bx = 0.f, by = 0.f;        // second chain for MLP
    int j = s;
    for (; j + 8 <= e; j += 8) {
        int2 p1 = epack[j + sub];
        int2 p2 = epack[j + 4 + sub];
        unsigned u1 = *(const unsigned*)(Hg + (size_t)p1.x * 64 + cp * 4);
        unsigned u2 = *(const unsigned*)(Hg + (size_t)p2.x * 64 + cp * 4);
        float w1 = __int_as_float(p1.y) * scales[(size_t)p1.x * 2 + half];
        float w2 = __int_as_float(p2.y) * scales[(size_t)p2.x * 2 + half];
        ax += w1 * (float)(short)(u1 & 0xFFFFu);
        ay += w1 * (float)(short)(u1 >> 16);
        bx += w2 * (float)(short)(u2 & 0xFFFFu);
        by += w2 * (float)(short)(u2 >> 16);
    }
    for (; j < e; j += 4) {
        int idx = j + sub;
        bool act = idx < e;
        int2 p = epack[act ? idx : s];
        unsigned u = *(const unsigned*)(Hg + (size_t)p.x * 64 + cp * 4);
        float wn = act ? __int_as_float(p.y) * scales[(size_t)p.x * 2 + half] : 0.f;
        ax += wn * (float)(short)(u & 0xFFFFu);
        ay += wn * (float)(short)(u >> 16);
    }
    ax += bx; ay += by;

    // reduce the 4 edge slots
    ax += __shfl_xor(ax, 16); ay += __shfl_xor(ay, 16);
    ax += __shfl_xor(ax, 32); ay += __shfl_xor(ay, 32);

    if (sub == 0) {
        int c = g * 32 + cp * 2;
        ax += bias[c]; ay += bias[c + 1];
        if (do_gelu) { ax = gelu_f(ax); ay = gelu_f(ay); }
        f32x2 v = {ax, ay};
        __builtin_nontemporal_store(v, (f32x2*)(out + (size_t)node * CH + c));
    }
}

// ---------------- launcher ----------------

extern "C" void kernel_launch(void* const* d_in, const int* in_sizes, int n_in,
                              void* d_out, int out_size, void* d_ws, size_t ws_size,
                              hipStream_t stream) {
    const float* x  = (const float*)d_in[0];
    const void*  ei = d_in[1];
    const float* W1 = (const float*)d_in[3]; const float* b1 = (const float*)d_in[4];
    const float* W2 = (const float*)d_in[5]; const float* b2 = (const float*)d_in[6];
    const float* W3 = (const float*)d_in[7]; const float* b3 = (const float*)d_in[8];

    int N = in_sizes[0] / CH;
    int E = in_sizes[1] / 2;
    float* out = (float*)d_out;

    char* ws = (char*)d_ws;
    auto take = [&](size_t bytes) {
        char* p = ws;
        ws += (bytes + 15) & ~(size_t)15;
        return p;
    };
    uint8_t*  H16    = (uint8_t*) take((size_t)N * 512);
    float*    scales = (float*)   take((size_t)N * 2 * sizeof(float));
    int*      deg    = (int*)     take((size_t)N * sizeof(int));
    float*    dis    = (float*)   take((size_t)N * sizeof(float));
    int*      rowptr = (int*)     take((size_t)(N + 1) * sizeof(int));
    int*      cnt    = (int*)     take((size_t)N * sizeof(int));
    int*      part   = (int*)     take(4096);
    int*      flag   = (int*)     take(16);
    int2*     epack  = (int2*)    take((size_t)E * sizeof(int2));
    _Float16* Wh1    = (_Float16*)take((size_t)CH * CH * 2);
    _Float16* Wl1    = (_Float16*)take((size_t)CH * CH * 2);
    _Float16* Wh2    = (_Float16*)take((size_t)CH * CH * 2);
    _Float16* Wl2    = (_Float16*)take((size_t)CH * CH * 2);
    _Float16* Wh3    = (_Float16*)take((size_t)CH * CH * 2);
    _Float16* Wl3    = (_Float16*)take((size_t)CH * CH * 2);

    hipMemsetAsync(deg, 0, (size_t)N * sizeof(int), stream);
    hipMemsetAsync(cnt, 0, (size_t)N * sizeof(int), stream);

    int eb = (E + 255) / 256;
    int nb = (N + 255) / 256;

    k_detect<<<1, 64, 0, stream>>>(ei, flag, E);
    k_deg<<<eb, 256, 0, stream>>>(ei, flag, deg, E);
    k_dis<<<nb, 256, 0, stream>>>(deg, dis, N);
    k_scan_block<<<nb, 256, 0, stream>>>(deg, rowptr, part, N);
    k_scan_partial<<<1, 256, 0, stream>>>(part, nb);
    k_add_off<<<nb, 256, 0, stream>>>(rowptr, part, N, E);
    k_scatter<<<eb, 256, 0, stream>>>(ei, flag, dis, rowptr, cnt, epack, E);

    k_split_w<<<CH, CH, 0, stream>>>(W1, Wh1, Wl1);
    k_split_w<<<CH, CH, 0, stream>>>(W2, Wh2, Wl2);
    k_split_w<<<CH, CH, 0, stream>>>(W3, Wh3, Wl3);

    dim3 ggrid((N + GM - 1) / GM, CH / GN);
    dim3 agrid(8 * ((N + 3) / 4));
    dim3 ablock(64, 4);

    // layer 1
    k_gemm16<<<ggrid, 256, 0, stream>>>(x, Wh1, Wl1, H16, scales, N);
    k_agg<<<agrid, ablock, 0, stream>>>(H16, scales, dis, rowptr, epack, b1, out, N, 1);
    // layer 2
    k_gemm16<<<ggrid, 256, 0, stream>>>(out, Wh2, Wl2, H16, scales, N);
    k_agg<<<agrid, ablock, 0, stream>>>(H16, scales, dis, rowptr, epack, b2, out, N, 1);
    // layer 3 (no gelu)
    k_gemm16<<<ggrid, 256, 0, stream>>>(out, Wh3, Wl3, H16, scales, N);
    k_agg<<<agrid, ablock, 0, stream>>>(H16, scales, dis, rowptr, epack, b3, out, N, 0);
}

// Round 8
// 440.385 us; speedup vs baseline: 1.6621x; 1.6621x over previous
//
#include <hip/hip_runtime.h>
#include <cstdint>
#include <cstddef>

#define CH 256      // all layers are 256-channel

typedef _Float16 f16x8 __attribute__((ext_vector_type(8)));
typedef _Float16 f16x4 __attribute__((ext_vector_type(4)));
typedef float f32x4 __attribute__((ext_vector_type(4)));

#define GLOB(x) ((const __attribute__((address_space(1))) void*)(x))
#define LDSP(x) ((__attribute__((address_space(3))) void*)(x))

// ---------------- helpers ----------------

__device__ __forceinline__ int ld_idx(const void* p, long long i, int w64) {
    if (w64) return (int)((const long long*)p)[i];
    return ((const int*)p)[i];
}

__device__ __forceinline__ float gelu_f(float x) {
    float x3 = x * x * x;
    float t = tanhf(0.7978845608028654f * (x + 0.044715f * x3));
    return 0.5f * x * (1.0f + t);
}

// ---------------- preprocessing ----------------

__global__ void k_detect(const void* __restrict__ ei, int* __restrict__ flag, int E) {
    int l = threadIdx.x;  // 0..63
    long long k = ((long long)l * (long long)(E - 1)) / 63;
    int w = ((const int*)ei)[2 * k + 1];
    unsigned long long vote = __ballot(w == 0);
    if (l == 0) *flag = (vote == ~0ULL) ? 1 : 0;
}

__global__ void k_deg(const void* __restrict__ ei, const int* __restrict__ flag,
                      int* __restrict__ deg, int E) {
    int e = blockIdx.x * blockDim.x + threadIdx.x;
    if (e >= E) return;
    int w64 = *flag;
    int d = ld_idx(ei, (long long)E + e, w64);
    atomicAdd(&deg[d], 1);
}

__global__ void k_dis(const int* __restrict__ deg, float* __restrict__ dis, int N) {
    int n = blockIdx.x * blockDim.x + threadIdx.x;
    if (n >= N) return;
    dis[n] = 1.0f / sqrtf((float)(deg[n] + 1));
}

__global__ void k_scan_block(const int* __restrict__ deg, int* __restrict__ rowptr,
                             int* __restrict__ partial, int N) {
    __shared__ int s[256];
    int gid = blockIdx.x * 256 + threadIdx.x;
    int v = (gid < N) ? deg[gid] : 0;
    s[threadIdx.x] = v;
    __syncthreads();
    for (int off = 1; off < 256; off <<= 1) {
        int t = (threadIdx.x >= off) ? s[threadIdx.x - off] : 0;
        __syncthreads();
        s[threadIdx.x] += t;
        __syncthreads();
    }
    if (gid < N) rowptr[gid] = s[threadIdx.x] - v;
    if (threadIdx.x == 255) partial[blockIdx.x] = s[255];
}

__global__ void k_scan_partial(int* __restrict__ partial, int nb) {
    __shared__ int s[256];
    int i = threadIdx.x;
    int v = (i < nb) ? partial[i] : 0;
    s[i] = v;
    __syncthreads();
    for (int off = 1; off < 256; off <<= 1) {
        int t = (i >= off) ? s[i - off] : 0;
        __syncthreads();
        s[i] += t;
        __syncthreads();
    }
    if (i < nb) partial[i] = s[i] - v;
}

__global__ void k_add_off(int* __restrict__ rowptr, const int* __restrict__ partial,
                          int N, int E) {
    int gid = blockIdx.x * 256 + threadIdx.x;
    if (gid < N) rowptr[gid] += partial[blockIdx.x];
    if (gid == 0) rowptr[N] = E;
}

__global__ void k_scatter(const void* __restrict__ ei, const int* __restrict__ flag,
                          const float* __restrict__ dis, const int* __restrict__ rowptr,
                          int* __restrict__ cnt, int2* __restrict__ epack, int E) {
    int e = blockIdx.x * blockDim.x + threadIdx.x;
    if (e >= E) return;
    int w64 = *flag;
    int s = ld_idx(ei, e, w64);
    int d = ld_idx(ei, (long long)E + e, w64);
    int pos = rowptr[d] + atomicAdd(&cnt[d], 1);
    epack[pos] = make_int2(s, __float_as_int(dis[s] * dis[d]));
}

// ---------------- weight split: W[k][c] fp32 -> Wt hi/lo fp16 [c][k] ----------------

__global__ void k_split_w(const float* __restrict__ W, _Float16* __restrict__ Wh,
                          _Float16* __restrict__ Wl) {
    int k = threadIdx.x;   // 0..255
    int c = blockIdx.x;    // 0..255
    float v = W[k * CH + c];
    _Float16 h = (_Float16)v;
    Wh[c * CH + k] = h;
    Wl[c * CH + k] = (_Float16)(v - (float)h);
}

// ---------------- x split: fp32 [N][256] -> Ah/Al fp16 planes ----------------

__global__ void k_split_x(const float* __restrict__ x, _Float16* __restrict__ Ah,
                          _Float16* __restrict__ Al, int n4) {
    int i = blockIdx.x * 256 + threadIdx.x;
    if (i >= n4) return;
    float4 v = ((const float4*)x)[i];
    f16x4 h, l;
    h[0] = (_Float16)v.x; l[0] = (_Float16)(v.x - (float)h[0]);
    h[1] = (_Float16)v.y; l[1] = (_Float16)(v.y - (float)h[1]);
    h[2] = (_Float16)v.z; l[2] = (_Float16)(v.z - (float)h[2]);
    h[3] = (_Float16)v.w; l[3] = (_Float16)(v.w - (float)h[3]);
    ((f16x4*)Ah)[i] = h;
    ((f16x4*)Al)[i] = l;
}

// ---------------- fp16x2 split GEMM (pre-split A), int16-quantized output ----------
// H16[M rows x 512 B] = quant16(A @ W); A = Ah+Al fp16 [M][256]; W = Bh/Bl [c][k].
// Per-(node,half) scale in scales[node*2+half].
// Block: 128x128 output, 4 waves of 64x64, MFMA 16x16x32_f16, K-step 32.

#define GM 128
#define GN 128
#define GK 32

__global__ __launch_bounds__(256, 2)
void k_gemm16s(const _Float16* __restrict__ Ah, const _Float16* __restrict__ Al,
               const _Float16* __restrict__ Bh, const _Float16* __restrict__ Bl,
               uint8_t* __restrict__ H16, float* __restrict__ scales, int M) {
    __shared__ __align__(16) char smem[65536];
    _Float16* lAh = (_Float16*)smem;            // [2][4096] = 16 KB
    _Float16* lAl = (_Float16*)(smem + 16384);
    _Float16* lBh = (_Float16*)(smem + 32768);
    _Float16* lBl = (_Float16*)(smem + 49152);

    const int tid  = threadIdx.x;
    const int lane = tid & 63;
    const int wid  = tid >> 6;
    const int m0   = blockIdx.x * GM;
    const int n0   = blockIdx.y * GN;
    const int wm   = wid >> 1, wn = wid & 1;
    const int r15  = lane & 15, kg = lane >> 4;

    // stage one K-step tile: 4 tensors x 512 chunks(16B) = 32 calls, 8/wave.
    // chunk L: row = L>>2, ch = L&3, source chunk swizzled ch ^ ((row>>1)&3).
    auto stage = [&](int buf, int k0) {
        #pragma unroll
        for (int c = 0; c < 8; c++) {
            int call = wid * 8 + c;                 // wave-uniform 0..31
            int cc = call & 7;
            int L = cc * 64 + lane;                 // 0..511
            int row = L >> 2, ch = L & 3;
            int sch = ch ^ ((row >> 1) & 3);
            if (call < 8) {
                int gr = m0 + row; gr = (gr < M) ? gr : (M - 1);
                const _Float16* g = Ah + (size_t)gr * CH + k0 + (sch << 3);
                __builtin_amdgcn_global_load_lds(GLOB(g), LDSP(&lAh[buf * 4096 + L * 8]), 16, 0, 0);
            } else if (call < 16) {
                int gr = m0 + row; gr = (gr < M) ? gr : (M - 1);
                const _Float16* g = Al + (size_t)gr * CH + k0 + (sch << 3);
                __builtin_amdgcn_global_load_lds(GLOB(g), LDSP(&lAl[buf * 4096 + L * 8]), 16, 0, 0);
            } else if (call < 24) {
                const _Float16* g = Bh + (size_t)(n0 + row) * CH + k0 + (sch << 3);
                __builtin_amdgcn_global_load_lds(GLOB(g), LDSP(&lBh[buf * 4096 + L * 8]), 16, 0, 0);
            } else {
                const _Float16* g = Bl + (size_t)(n0 + row) * CH + k0 + (sch << 3);
                __builtin_amdgcn_global_load_lds(GLOB(g), LDSP(&lBl[buf * 4096 + L * 8]), 16, 0, 0);
            }
        }
    };

    f32x4 acc[4][4];
    #pragma unroll
    for (int i = 0; i < 4; i++)
        #pragma unroll
        for (int n = 0; n < 4; n++)
            acc[i][n] = (f32x4){0.f, 0.f, 0.f, 0.f};

    stage(0, 0);
    __syncthreads();

    for (int ks = 0; ks < 8; ks++) {
        int cur = ks & 1;
        if (ks < 7) stage(cur ^ 1, (ks + 1) * GK);

        f16x8 ah[4], al[4], bh[4], bl[4];
        #pragma unroll
        for (int i = 0; i < 4; i++) {
            int R = wm * 64 + i * 16 + r15;
            int p = kg ^ ((R >> 1) & 3);
            ah[i] = *(const f16x8*)&lAh[cur * 4096 + R * GK + p * 8];
            al[i] = *(const f16x8*)&lAl[cur * 4096 + R * GK + p * 8];
        }
        #pragma unroll
        for (int n = 0; n < 4; n++) {
            int C = wn * 64 + n * 16 + r15;
            int p = kg ^ ((C >> 1) & 3);
            bh[n] = *(const f16x8*)&lBh[cur * 4096 + C * GK + p * 8];
            bl[n] = *(const f16x8*)&lBl[cur * 4096 + C * GK + p * 8];
        }
        #pragma unroll
        for (int i = 0; i < 4; i++)
            #pragma unroll
            for (int n = 0; n < 4; n++) {
                acc[i][n] = __builtin_amdgcn_mfma_f32_16x16x32_f16(ah[i], bh[n], acc[i][n], 0, 0, 0);
                acc[i][n] = __builtin_amdgcn_mfma_f32_16x16x32_f16(ah[i], bl[n], acc[i][n], 0, 0, 0);
                acc[i][n] = __builtin_amdgcn_mfma_f32_16x16x32_f16(al[i], bh[n], acc[i][n], 0, 0, 0);
            }
        __syncthreads();
    }

    // ---- epilogue: tile absmax -> scale, transpose via LDS, int16 store ----
    float mx = 0.f;
    #pragma unroll
    for (int i = 0; i < 4; i++)
        #pragma unroll
        for (int n = 0; n < 4; n++)
            #pragma unroll
            for (int r = 0; r < 4; r++)
                mx = fmaxf(mx, fabsf(acc[i][n][r]));
    #pragma unroll
    for (int off = 32; off > 0; off >>= 1)
        mx = fmaxf(mx, __shfl_xor(mx, off));
    if (lane == 0) ((float*)smem)[wid] = mx;
    __syncthreads();
    float tmax = fmaxf(fmaxf(((float*)smem)[0], ((float*)smem)[1]),
                       fmaxf(((float*)smem)[2], ((float*)smem)[3]));
    float scl = tmax * (1.0f / 32767.0f);
    float inv = (tmax > 0.f) ? (32767.0f / tmax) : 0.f;
    __syncthreads();

    float* ep = (float*)smem + wid * 4096;   // 64x64 fp32 tile per wave (16 KB)
    #pragma unroll
    for (int i = 0; i < 4; i++)
        #pragma unroll
        for (int n = 0; n < 4; n++)
            #pragma unroll
            for (int r = 0; r < 4; r++)
                ep[(i * 16 + kg * 4 + r) * 64 + n * 16 + r15] = acc[i][n][r];
    __syncthreads();

    int q = lane & 15;            // channel quad within tile
    int rsub = lane >> 4;         // row sub-index
    #pragma unroll
    for (int p = 0; p < 16; p++) {
        int lrow = p * 4 + rsub;                    // 0..63
        int grow = m0 + wm * 64 + lrow;
        if (grow < M) {
            int q0 = __float2int_rn(ep[lrow * 64 + q * 4 + 0] * inv);
            int q1 = __float2int_rn(ep[lrow * 64 + q * 4 + 1] * inv);
            int q2 = __float2int_rn(ep[lrow * 64 + q * 4 + 2] * inv);
            int q3 = __float2int_rn(ep[lrow * 64 + q * 4 + 3] * inv);
            uint2 d;
            d.x = (q0 & 0xFFFF) | (q1 << 16);
            d.y = (q2 & 0xFFFF) | (q3 << 16);
            int col = n0 + wn * 64 + q * 4;
            *(uint2*)(H16 + (size_t)grow * 512 + (size_t)col * 2) = d;
        }
    }

    if (tid < GM && m0 + tid < M) scales[(size_t)(m0 + tid) * 2 + (n0 >> 7)] = scl;
}

// ---------------- sparse aggregation (gather-CSR over int16 H) ----------------
// out[n] = dis[n]^2*h[n] + sum_e norm_e * h[src_e] (+bias)
// MODE 0: gelu + split-fp16 store to Ah/Al (layers 1,2)
// MODE 1: fp32 store to out (layer 3, no gelu)

template <int MODE>
__global__ __launch_bounds__(256) void k_agg(const uint8_t* __restrict__ H16,
                                             const float* __restrict__ scales,
                                             const float* __restrict__ dis,
                                             const int* __restrict__ rowptr,
                                             const int2* __restrict__ epack,
                                             const float* __restrict__ bias,
                                             float* __restrict__ out,
                                             _Float16* __restrict__ Ah,
                                             _Float16* __restrict__ Al, int N) {
    int node = blockIdx.x * 4 + threadIdx.y;
    if (node >= N) return;
    int lane = threadIdx.x;  // 0..63
    int half = lane >> 5;
    float d = dis[node];
    short4 hv = *(const short4*)(H16 + (size_t)node * 512 + (size_t)lane * 8);
    float wself = d * d * scales[(size_t)node * 2 + half];
    float ax = wself * (float)hv.x, ay = wself * (float)hv.y;
    float az = wself * (float)hv.z, aw = wself * (float)hv.w;
    int s = rowptr[node], e = rowptr[node + 1];
    int j = s;
    for (; j + 8 <= e; j += 8) {
        int2 p[8];
        #pragma unroll
        for (int t = 0; t < 8; t++) p[t] = epack[j + t];
        short4 v[8];
        float sc[8];
        #pragma unroll
        for (int t = 0; t < 8; t++) {
            v[t] = *(const short4*)(H16 + (size_t)p[t].x * 512 + (size_t)lane * 8);
            sc[t] = scales[(size_t)p[t].x * 2 + half];
        }
        #pragma unroll
        for (int t = 0; t < 8; t++) {
            float wn = __int_as_float(p[t].y) * sc[t];
            ax += wn * (float)v[t].x; ay += wn * (float)v[t].y;
            az += wn * (float)v[t].z; aw += wn * (float)v[t].w;
        }
    }
    for (; j < e; j++) {
        int2 p = epack[j];
        float wn = __int_as_float(p.y) * scales[(size_t)p.x * 2 + half];
        short4 v = *(const short4*)(H16 + (size_t)p.x * 512 + (size_t)lane * 8);
        ax += wn * (float)v.x; ay += wn * (float)v.y;
        az += wn * (float)v.z; aw += wn * (float)v.w;
    }
    float4 b = ((const float4*)bias)[lane];
    ax += b.x; ay += b.y; az += b.z; aw += b.w;
    if (MODE == 0) {
        ax = gelu_f(ax); ay = gelu_f(ay); az = gelu_f(az); aw = gelu_f(aw);
        f16x4 h, l;
        h[0] = (_Float16)ax; l[0] = (_Float16)(ax - (float)h[0]);
        h[1] = (_Float16)ay; l[1] = (_Float16)(ay - (float)h[1]);
        h[2] = (_Float16)az; l[2] = (_Float16)(az - (float)h[2]);
        h[3] = (_Float16)aw; l[3] = (_Float16)(aw - (float)h[3]);
        size_t idx = (size_t)node * 64 + lane;
        ((f16x4*)Ah)[idx] = h;
        ((f16x4*)Al)[idx] = l;
    } else {
        ((float4*)(out + (size_t)node * CH))[lane] = make_float4(ax, ay, az, aw);
    }
}

// ---------------- launcher ----------------

extern "C" void kernel_launch(void* const* d_in, const int* in_sizes, int n_in,
                              void* d_out, int out_size, void* d_ws, size_t ws_size,
                              hipStream_t stream) {
    const float* x  = (const float*)d_in[0];
    const void*  ei = d_in[1];
    const float* W1 = (const float*)d_in[3]; const float* b1 = (const float*)d_in[4];
    const float* W2 = (const float*)d_in[5]; const float* b2 = (const float*)d_in[6];
    const float* W3 = (const float*)d_in[7]; const float* b3 = (const float*)d_in[8];

    int N = in_sizes[0] / CH;
    int E = in_sizes[1] / 2;
    float* out = (float*)d_out;

    char* ws = (char*)d_ws;
    auto take = [&](size_t bytes) {
        char* p = ws;
        ws += (bytes + 15) & ~(size_t)15;
        return p;
    };
    uint8_t*  H16    = (uint8_t*) take((size_t)N * 512);
    _Float16* Ah     = (_Float16*)take((size_t)N * CH * 2);
    _Float16* Al     = (_Float16*)take((size_t)N * CH * 2);
    float*    scales = (float*)   take((size_t)N * 2 * sizeof(float));
    int*      deg    = (int*)     take((size_t)N * sizeof(int));
    float*    dis    = (float*)   take((size_t)N * sizeof(float));
    int*      rowptr = (int*)     take((size_t)(N + 1) * sizeof(int));
    int*      cnt    = (int*)     take((size_t)N * sizeof(int));
    int*      part   = (int*)     take(4096);
    int*      flag   = (int*)     take(16);
    int2*     epack  = (int2*)    take((size_t)E * sizeof(int2));
    _Float16* Wh1    = (_Float16*)take((size_t)CH * CH * 2);
    _Float16* Wl1    = (_Float16*)take((size_t)CH * CH * 2);
    _Float16* Wh2    = (_Float16*)take((size_t)CH * CH * 2);
    _Float16* Wl2    = (_Float16*)take((size_t)CH * CH * 2);
    _Float16* Wh3    = (_Float16*)take((size_t)CH * CH * 2);
    _Float16* Wl3    = (_Float16*)take((size_t)CH * CH * 2);

    hipMemsetAsync(deg, 0, (size_t)N * sizeof(int), stream);
    hipMemsetAsync(cnt, 0, (size_t)N * sizeof(int), stream);

    int eb = (E + 255) / 256;
    int nb = (N + 255) / 256;

    k_detect<<<1, 64, 0, stream>>>(ei, flag, E);
    k_deg<<<eb, 256, 0, stream>>>(ei, flag, deg, E);
    k_dis<<<nb, 256, 0, stream>>>(deg, dis, N);
    k_scan_block<<<nb, 256, 0, stream>>>(deg, rowptr, part, N);
    k_scan_partial<<<1, 256, 0, stream>>>(part, nb);
    k_add_off<<<nb, 256, 0, stream>>>(rowptr, part, N, E);
    k_scatter<<<eb, 256, 0, stream>>>(ei, flag, dis, rowptr, cnt, epack, E);

    k_split_w<<<CH, CH, 0, stream>>>(W1, Wh1, Wl1);
    k_split_w<<<CH, CH, 0, stream>>>(W2, Wh2, Wl2);
    k_split_w<<<CH, CH, 0, stream>>>(W3, Wh3, Wl3);

    int n4 = N * (CH / 4);
    k_split_x<<<(n4 + 255) / 256, 256, 0, stream>>>(x, Ah, Al, n4);

    dim3 ggrid((N + GM - 1) / GM, CH / GN);
    dim3 agrid((N + 3) / 4);
    dim3 ablock(64, 4);

    // layer 1
    k_gemm16s<<<ggrid, 256, 0, stream>>>(Ah, Al, Wh1, Wl1, H16, scales, N);
    k_agg<0><<<agrid, ablock, 0, stream>>>(H16, scales, dis, rowptr, epack, b1, out, Ah, Al, N);
    // layer 2
    k_gemm16s<<<ggrid, 256, 0, stream>>>(Ah, Al, Wh2, Wl2, H16, scales, N);
    k_agg<0><<<agrid, ablock, 0, stream>>>(H16, scales, dis, rowptr, epack, b2, out, Ah, Al, N);
    // layer 3 (no gelu, fp32 out)
    k_gemm16s<<<ggrid, 256, 0, stream>>>(Ah, Al, Wh3, Wl3, H16, scales, N);
    k_agg<1><<<agrid, ablock, 0, stream>>>(H16, scales, dis, rowptr, epack, b3, out, Ah, Al, N);
}